// Round 9
// baseline (1291.323 us; speedup 1.0000x reference)
//
#include <hip/hip_runtime.h>
#include <math.h>

#define BATCH 1024
#define TSEQ  2048
#define DIN   5
#define H     64
#define BT    4      // elems per block; grid 256, 256-thread blocks -> 2 blocks/CU
#define SSTR  160    // halves/elem: [h1 64 | h2 64 | x 32]; word-stride 80 = 16 mod 32 -> 2-way banks (free)
#define NOUT  128

typedef _Float16 f16x8 __attribute__((ext_vector_type(8)));
typedef float    f32x4 __attribute__((ext_vector_type(4)));

#if __has_builtin(__builtin_amdgcn_rcpf)
__device__ __forceinline__ float rcp_fast(float x) { return __builtin_amdgcn_rcpf(x); }
#else
__device__ __forceinline__ float rcp_fast(float x) { return 1.0f / x; }
#endif

#define LOG2E 1.44269504088896f

// exp2-based activations; weights/biases pre-scaled by log2e (sigmoid) or
// 2*log2e (tanh gate) so no per-use multiply.
__device__ __forceinline__ float sigm2(float s) {   // s = log2e * p
    return rcp_fast(1.0f + __builtin_amdgcn_exp2f(-s));
}
__device__ __forceinline__ float tanh2(float s) {   // s = 2*log2e * p
    return fmaf(-2.0f, rcp_fast(__builtin_amdgcn_exp2f(s) + 1.0f), 1.0f);
}

// 256-thread block = 4 waves, BT=4 elems, grid 256 -> 2 independent blocks/CU.
// Each wave owns h-units [16w,16w+16) for BOTH layers: 28 MFMA/wave
// (lay1 K=96 with x folded in; lay2 K=128), A = state with elem = m>>2 so
// D rows 4q+r are all elem q (reg 0, no selects). Each lane then runs two
// fully in-register G tasks (lay1 + lay2) for (hu, elem=q). Bias via MFMA C;
// exp2 pre-scaled weights. One barrier/timestep, double-buffered 2.5 KB state.
// Two co-resident blocks drift out of phase -> one block's MFMA overlaps the
// other's VALU/trans G phase (r8 was phase-locked: MfmaUtil+VALUBusy ~ sum).
__global__ __launch_bounds__(256)
void lstm_mfma(const float* __restrict__ x,
               const float* __restrict__ Wih0, const float* __restrict__ Whh0,
               const float* __restrict__ bih0, const float* __restrict__ bhh0,
               const float* __restrict__ Wih1, const float* __restrict__ Whh1,
               const float* __restrict__ bih1, const float* __restrict__ bhh1,
               const float* __restrict__ Wfc,  const float* __restrict__ bfc,
               float* __restrict__ out)
{
    __shared__ alignas(16) _Float16 S[2][BT * SSTR];   // 2.5 KB state, double-buffered
    __shared__ alignas(16) float    h2f[BT][H];        // 1 KB final h2 for FC

    const int tid  = threadIdx.x;
    const int w    = tid >> 6;         // 0..3: h-unit tile AND x-staging elem
    const int lane = tid & 63;
    const int col  = lane & 15;        // n (gate-row offset) and A-row m
    const int q    = lane >> 4;        // quad -> k-slice for A/B frags; G elem
    const int hu   = 16 * w + col;
    const int b0   = blockIdx.x * BT;

    // ---- zero both state buffers (x pad must stay 0) ----
    for (int j = tid; j < 2 * BT * SSTR; j += 256)
        ((_Float16*)S)[j] = (_Float16)0.0f;

    const float sgl[4] = {LOG2E, LOG2E, 2.0f * LOG2E, LOG2E};  // i,f,g,o

    // ---- B-fragments for BOTH layers (registers, pre-scaled) ----
    // B[k=q*8+j][n=col]; n-tile g = gate rows g*64 + hu.
    f16x8 B1[4][3];   // lay1: [Whh0 k0-31 | Whh0 k32-63 | Wih0 (5 of 32)]
    f16x8 B2[4][4];   // lay2: [Wih1 k0-31 | Wih1 k32-63 | Whh1 k0-31 | Whh1 k32-63]
    f32x4 bC1[4], bC2[4];
    #pragma unroll
    for (int g = 0; g < 4; ++g) {
        const int   row = g * 64 + hu;
        const float sg  = sgl[g];
        #pragma unroll
        for (int kt = 0; kt < 2; ++kt) {
            f16x8 f0, f1, f2;
            #pragma unroll
            for (int j = 0; j < 8; ++j) {
                f0[j] = (_Float16)(Whh0[row * H + kt * 32 + q * 8 + j] * sg);
                f1[j] = (_Float16)(Wih1[row * H + kt * 32 + q * 8 + j] * sg);
                f2[j] = (_Float16)(Whh1[row * H + kt * 32 + q * 8 + j] * sg);
            }
            B1[g][kt]     = f0;
            B2[g][kt]     = f1;
            B2[g][2 + kt] = f2;
        }
        {   // lay1 k-tile 2: Wih0 (K-local 0..31, only 0..4 nonzero)
            f16x8 f;
            #pragma unroll
            for (int j = 0; j < 8; ++j) {
                const int kk = q * 8 + j;
                f[j] = (_Float16)(kk < DIN ? Wih0[row * DIN + kk] * sg : 0.0f);
            }
            B1[g][2] = f;
        }
        const float b1 = (bih0[row] + bhh0[row]) * sg;
        const float b2 = (bih1[row] + bhh1[row]) * sg;
        bC1[g] = f32x4{b1, b1, b1, b1};
        bC2[g] = f32x4{b2, b2, b2, b2};
    }

    // ---- x staging: wave w stages elem w, lanes 0..4 = dims ----
    const bool xlane = (lane < DIN);
    __syncthreads();                       // zero-fill done
    if (xlane)
        S[1][w * SSTR + 128 + lane] =
            (_Float16)x[(size_t)(b0 + w) * TSEQ * DIN + lane];   // x(t=0)

    const int abase = (col >> 2) * SSTR + q * 8;   // A row m=col supplies elem col>>2
    float c1 = 0.0f, c2 = 0.0f, h2fin = 0.0f;

    __syncthreads();

    // ============ main loop: iter i = layer-1(t=i) & layer-2(t=i-1) ============
    #pragma unroll 1
    for (int i = 0; i <= TSEQ; ++i) {
        const _Float16* rb = S[(i + 1) & 1];
        _Float16*       wb = S[i & 1];

        // prefetch next x early (hides global latency under MFMA)
        float xn = 0.0f;
        const bool xld = xlane && (i + 1 < TSEQ);
        if (xld)
            xn = x[(size_t)(b0 + w) * TSEQ * DIN + (i + 1) * DIN + lane];

        // A-fragments (5 x ds_read_b128)
        f16x8 a0 = *(const f16x8*)&rb[abase];          // h1 k 0..31
        f16x8 a1 = *(const f16x8*)&rb[abase + 32];     // h1 k 32..63
        f16x8 ah0 = *(const f16x8*)&rb[abase + 64];    // h2 k 0..31
        f16x8 ah1 = *(const f16x8*)&rb[abase + 96];    // h2 k 32..63
        f16x8 ax  = *(const f16x8*)&rb[abase + 128];   // x (pad 0)

        f32x4 d1[4], d2[4];
        #pragma unroll
        for (int g = 0; g < 4; ++g) {
            d1[g] = __builtin_amdgcn_mfma_f32_16x16x32_f16(a0, B1[g][0], bC1[g], 0, 0, 0);
            d1[g] = __builtin_amdgcn_mfma_f32_16x16x32_f16(a1, B1[g][1], d1[g], 0, 0, 0);
            d1[g] = __builtin_amdgcn_mfma_f32_16x16x32_f16(ax, B1[g][2], d1[g], 0, 0, 0);
        }
        #pragma unroll
        for (int g = 0; g < 4; ++g) {
            d2[g] = __builtin_amdgcn_mfma_f32_16x16x32_f16(a0,  B2[g][0], bC2[g], 0, 0, 0);
            d2[g] = __builtin_amdgcn_mfma_f32_16x16x32_f16(a1,  B2[g][1], d2[g], 0, 0, 0);
            d2[g] = __builtin_amdgcn_mfma_f32_16x16x32_f16(ah0, B2[g][2], d2[g], 0, 0, 0);
            d2[g] = __builtin_amdgcn_mfma_f32_16x16x32_f16(ah1, B2[g][3], d2[g], 0, 0, 0);
        }

        // ---- G: two in-register tasks per lane (hu, elem=q), reg 0 only ----
        if (i < TSEQ) {   // layer-1 for t = i
            float iv = sigm2(d1[0][0]);
            float fv = sigm2(d1[1][0]);
            float gv = tanh2(d1[2][0]);
            float ov = sigm2(d1[3][0]);
            c1 = fmaf(fv, c1, iv * gv);
            wb[q * SSTR + hu] = (_Float16)(ov * tanh2(2.0f * LOG2E * c1));
        }
        if (i > 0) {      // layer-2 for t = i-1
            float iv = sigm2(d2[0][0]);
            float fv = sigm2(d2[1][0]);
            float gv = tanh2(d2[2][0]);
            float ov = sigm2(d2[3][0]);
            c2 = fmaf(fv, c2, iv * gv);
            h2fin = ov * tanh2(2.0f * LOG2E * c2);
            wb[q * SSTR + 64 + hu] = (_Float16)h2fin;
        }
        if (xld)
            wb[w * SSTR + 128 + lane] = (_Float16)xn;   // x(t=i+1)

        __syncthreads();
    }

    // ---------------- epilogue: out = relu(h2(T-1) @ Wfc^T + bfc) ----------------
    h2f[q][hu] = h2fin;                // (q, hu) unique across the 256 lanes
    __syncthreads();
    {
        const int o  = tid & (NOUT - 1);   // 0..127
        const int e0 = tid >> 7;           // 0 or 1; also handles e0+2
        const float4* wr = (const float4*)(Wfc + o * H);
        float4 wv[H / 4];
        #pragma unroll
        for (int k = 0; k < H / 4; ++k) wv[k] = wr[k];
        const float bo = bfc[o];
        #pragma unroll
        for (int rep = 0; rep < 2; ++rep) {
            const int e = e0 + 2 * rep;
            const float* hv = h2f[e];
            float s0 = 0.f, s1 = 0.f, s2 = 0.f, s3 = 0.f;
            #pragma unroll
            for (int k = 0; k < H / 4; ++k) {
                float4 v = wv[k];
                s0 = fmaf(v.x, hv[4 * k + 0], s0);
                s1 = fmaf(v.y, hv[4 * k + 1], s1);
                s2 = fmaf(v.z, hv[4 * k + 2], s2);
                s3 = fmaf(v.w, hv[4 * k + 3], s3);
            }
            float acc = bo + (s0 + s1) + (s2 + s3);
            out[(size_t)(b0 + e) * NOUT + o] = fmaxf(acc, 0.0f);
        }
    }
}

extern "C" void kernel_launch(void* const* d_in, const int* in_sizes, int n_in,
                              void* d_out, int out_size, void* d_ws, size_t ws_size,
                              hipStream_t stream) {
    const float* x    = (const float*)d_in[0];
    const float* Wih0 = (const float*)d_in[1];
    const float* Whh0 = (const float*)d_in[2];
    const float* bih0 = (const float*)d_in[3];
    const float* bhh0 = (const float*)d_in[4];
    const float* Wih1 = (const float*)d_in[5];
    const float* Whh1 = (const float*)d_in[6];
    const float* bih1 = (const float*)d_in[7];
    const float* bhh1 = (const float*)d_in[8];
    const float* Wfc  = (const float*)d_in[9];
    const float* bfc  = (const float*)d_in[10];
    float* out = (float*)d_out;

    lstm_mfma<<<dim3(BATCH / BT), dim3(256), 0, stream>>>(
        x, Wih0, Whh0, bih0, bhh0, Wih1, Whh1, bih1, bhh1, Wfc, bfc, out);
}

// Round 10
// 1178.309 us; speedup vs baseline: 1.0959x; 1.0959x over previous
//
#include <hip/hip_runtime.h>
#include <math.h>

#define BATCH 1024
#define TSEQ  2048
#define DIN   5
#define H     64
#define BT    4      // elems per block; grid 256 = 1 block per CU (full chip)
#define NOUT  128
#define DEP   8      // ring depth in timesteps
#define R1E   96     // ring1 per-elem halves: [h1 64 | x 32]; 48 words -> 2-way banks (free)
#define R2E   80     // ring2 per-elem halves: [h2 64 | pad 16]; 40 words -> 2-way banks (free)

typedef _Float16 f16x8 __attribute__((ext_vector_type(8)));
typedef float    f32x4 __attribute__((ext_vector_type(4)));

#if __has_builtin(__builtin_amdgcn_rcpf)
__device__ __forceinline__ float rcp_fast(float x) { return __builtin_amdgcn_rcpf(x); }
#else
__device__ __forceinline__ float rcp_fast(float x) { return 1.0f / x; }
#endif

#define LOG2E 1.44269504088896f

__device__ __forceinline__ float sigm2(float s) {   // s = log2e * p
    return rcp_fast(1.0f + __builtin_amdgcn_exp2f(-s));
}
__device__ __forceinline__ float tanh2(float s) {   // s = 2*log2e * p
    return fmaf(-2.0f, rcp_fast(__builtin_amdgcn_exp2f(s) + 1.0f), 1.0f);
}

// acquire-poll an LDS counter until >= v (value is wave-uniform; one ds_read, broadcast)
__device__ __forceinline__ void spin_ge(int* p, int v) {
    while (__hip_atomic_load(p, __ATOMIC_ACQUIRE, __HIP_MEMORY_SCOPE_WORKGROUP) < v)
        __builtin_amdgcn_s_sleep(1);
}

// Barrier-free producer-consumer LSTM. Grid 256, 512-thread blocks, BT=4.
// Waves 0-3 (lay-1): 12 MFMA (K=96, x folded) + in-register G1, publish h1+x
// into ring1[DEP] and bump done1. Waves 4-7 (lay-2): 16 MFMA (K=128) + G2,
// publish h2 into ring2[DEP], bump done2. NO __syncthreads in the main loop:
// waves sync only on the counters they depend on, so lay-1 runs ahead of
// lay-2 and each SIMD's lay-1 MFMA overlaps its lay-2 trans (and vice versa).
// A = state with elem = m>>2 -> D reg 0 is elem q for every lane (no selects).
// Bias via MFMA C operand; exp2-prescaled weights (r8 numerics, absmax 9.8e-4).
__global__ __launch_bounds__(512)
void lstm_pipe(const float* __restrict__ x,
               const float* __restrict__ Wih0, const float* __restrict__ Whh0,
               const float* __restrict__ bih0, const float* __restrict__ bhh0,
               const float* __restrict__ Wih1, const float* __restrict__ Whh1,
               const float* __restrict__ bih1, const float* __restrict__ bhh1,
               const float* __restrict__ Wfc,  const float* __restrict__ bfc,
               float* __restrict__ out)
{
    __shared__ alignas(16) _Float16 ring1[DEP][BT * R1E];  // 6 KB  [h1 | x]
    __shared__ alignas(16) _Float16 ring2[DEP][BT * R2E];  // 5 KB  [h2]
    __shared__ alignas(16) float    h2f[BT][H];            // 1 KB  FC input
    __shared__ int done1, done2;

    const int tid  = threadIdx.x;
    const int w    = tid >> 6;         // 0..7
    const int lane = tid & 63;
    const int col  = lane & 15;        // n (h-unit offset); A-row m
    const int q    = lane >> 4;        // quad -> G elem; k-slice
    const int ww   = w & 3;            // h-unit tile
    const int lay  = w >> 2;           // 0 = layer-1 producer, 1 = layer-2 consumer
    const int hu   = 16 * ww + col;
    const int b0   = blockIdx.x * BT;

    // ---- init rings (x pad area must be zero forever) + counters ----
    for (int j = tid; j < DEP * BT * R1E; j += 512) ((_Float16*)ring1)[j] = (_Float16)0.0f;
    for (int j = tid; j < DEP * BT * R2E; j += 512) ((_Float16*)ring2)[j] = (_Float16)0.0f;
    if (tid == 0) { done1 = 0; done2 = 0; }

    const float sgl[4] = {LOG2E, LOG2E, 2.0f * LOG2E, LOG2E};  // i,f,g,o

    // ---- B-fragments for THIS wave's layer (registers, pre-scaled) ----
    // B[k=q*8+j][n=col]; n-tile g = gate rows g*64 + hu.
    // lay0: [0]=Whh0 k0-31 [1]=Whh0 k32-63 [2]=Wih0 (5 of 32) [3]=unused
    // lay1: [0]=Wih1 k0-31 [1]=Wih1 k32-63 [2]=Whh1 k0-31 [3]=Whh1 k32-63
    f16x8 Bf[4][4];
    f32x4 bC[4];
    #pragma unroll
    for (int g = 0; g < 4; ++g) {
        const int   row = g * 64 + hu;
        const float sg  = sgl[g];
        const float* Wa = lay ? (Wih1 + row * H) : (Whh0 + row * H);
        f16x8 f0, f1, f2, f3;
        #pragma unroll
        for (int j = 0; j < 8; ++j) {
            f0[j] = (_Float16)(Wa[q * 8 + j] * sg);
            f1[j] = (_Float16)(Wa[32 + q * 8 + j] * sg);
        }
        if (lay) {
            const float* Wb = Whh1 + row * H;
            #pragma unroll
            for (int j = 0; j < 8; ++j) {
                f2[j] = (_Float16)(Wb[q * 8 + j] * sg);
                f3[j] = (_Float16)(Wb[32 + q * 8 + j] * sg);
            }
        } else {
            #pragma unroll
            for (int j = 0; j < 8; ++j) {
                const int kk = q * 8 + j;
                f2[j] = (_Float16)(kk < DIN ? Wih0[row * DIN + kk] * sg : 0.0f);
                f3[j] = (_Float16)0.0f;
            }
        }
        Bf[g][0] = f0; Bf[g][1] = f1; Bf[g][2] = f2; Bf[g][3] = f3;
        const float bb = (lay ? (bih1[row] + bhh1[row])
                              : (bih0[row] + bhh0[row])) * sg;
        bC[g] = f32x4{bb, bb, bb, bb};
    }

    __syncthreads();   // rings zeroed
    if (lay == 0 && lane < DIN)   // stage x(t=0) into slot DEP-1
        ring1[DEP - 1][ww * R1E + 64 + lane] =
            (_Float16)x[(size_t)(b0 + ww) * TSEQ * DIN + lane];
    __syncthreads();   // x(0) staged; pipeline starts

    if (lay == 0) {
        // ================= layer-1 producer =================
        const float* xp = x + (size_t)(b0 + ww) * TSEQ * DIN;
        const int ab = (col >> 2) * R1E + q * 8;
        float c1 = 0.0f;
        #pragma unroll 1
        for (int t = 0; t < TSEQ; ++t) {
            if (t >= DEP) spin_ge(&done2, 4 * (t - DEP + 1));  // ring1 WAR vs lay2 readers
            spin_ge(&done1, 4 * t);                            // h1(t-1) from all lay1 waves
            float xn = 0.0f;
            const bool xld = (lane < DIN) && (t + 1 < TSEQ);
            if (xld) xn = xp[(t + 1) * DIN + lane];            // prefetch x(t+1)

            const _Float16* rb = ring1[(t + DEP - 1) % DEP];
            f16x8 a0 = *(const f16x8*)&rb[ab];          // h1 k 0..31
            f16x8 a1 = *(const f16x8*)&rb[ab + 32];     // h1 k 32..63
            f16x8 ax = *(const f16x8*)&rb[ab + 64];     // x (pad 0)
            f32x4 d[4];
            #pragma unroll
            for (int g = 0; g < 4; ++g) {
                d[g] = __builtin_amdgcn_mfma_f32_16x16x32_f16(a0, Bf[g][0], bC[g], 0, 0, 0);
                d[g] = __builtin_amdgcn_mfma_f32_16x16x32_f16(a1, Bf[g][1], d[g], 0, 0, 0);
                d[g] = __builtin_amdgcn_mfma_f32_16x16x32_f16(ax, Bf[g][2], d[g], 0, 0, 0);
            }
            float iv = sigm2(d[0][0]);
            float fv = sigm2(d[1][0]);
            float gv = tanh2(d[2][0]);
            float ov = sigm2(d[3][0]);
            c1 = fmaf(fv, c1, iv * gv);
            _Float16* wb = ring1[t % DEP];
            wb[q * R1E + hu] = (_Float16)(ov * tanh2(2.0f * LOG2E * c1));  // h1(t)
            if (xld) wb[ww * R1E + 64 + lane] = (_Float16)xn;              // x(t+1)
            __threadfence_block();          // drain this wave's ds writes
            if (lane == 0) atomicAdd(&done1, 1);
        }
    } else {
        // ================= layer-2 consumer =================
        const int ab1 = (col >> 2) * R1E + q * 8;
        const int ab2 = (col >> 2) * R2E + q * 8;
        float c2 = 0.0f, h2fin = 0.0f;
        #pragma unroll 1
        for (int t = 0; t < TSEQ; ++t) {
            spin_ge(&done2, 4 * t);          // h2(t-1) from all lay2 waves
            spin_ge(&done1, 4 * (t + 1));    // y1(t) published by all lay1 waves
            const _Float16* ry = ring1[t % DEP];
            const _Float16* rh = ring2[(t + DEP - 1) % DEP];
            f16x8 ay0 = *(const f16x8*)&ry[ab1];         // y1(t) k 0..31
            f16x8 ay1 = *(const f16x8*)&ry[ab1 + 32];    // y1(t) k 32..63
            f16x8 ah0 = *(const f16x8*)&rh[ab2];         // h2(t-1) k 0..31
            f16x8 ah1 = *(const f16x8*)&rh[ab2 + 32];    // h2(t-1) k 32..63
            f32x4 d[4];
            #pragma unroll
            for (int g = 0; g < 4; ++g) {
                d[g] = __builtin_amdgcn_mfma_f32_16x16x32_f16(ah0, Bf[g][2], bC[g], 0, 0, 0);
                d[g] = __builtin_amdgcn_mfma_f32_16x16x32_f16(ah1, Bf[g][3], d[g], 0, 0, 0);
                d[g] = __builtin_amdgcn_mfma_f32_16x16x32_f16(ay0, Bf[g][0], d[g], 0, 0, 0);
                d[g] = __builtin_amdgcn_mfma_f32_16x16x32_f16(ay1, Bf[g][1], d[g], 0, 0, 0);
            }
            float iv = sigm2(d[0][0]);
            float fv = sigm2(d[1][0]);
            float gv = tanh2(d[2][0]);
            float ov = sigm2(d[3][0]);
            c2 = fmaf(fv, c2, iv * gv);
            h2fin = ov * tanh2(2.0f * LOG2E * c2);
            ring2[t % DEP][q * R2E + hu] = (_Float16)h2fin;   // h2(t)
            __threadfence_block();
            if (lane == 0) atomicAdd(&done2, 1);
        }
        h2f[q][hu] = h2fin;                 // h2(T-1)
    }

    __syncthreads();

    // ---------------- epilogue: out = relu(h2(T-1) @ Wfc^T + bfc) ----------------
    {
        const int e = tid >> 7;             // 0..3
        const int o = tid & (NOUT - 1);     // 0..127
        const float4* wr = (const float4*)(Wfc + o * H);
        const float*  hv = h2f[e];
        float s0 = 0.f, s1 = 0.f, s2 = 0.f, s3 = 0.f;
        #pragma unroll
        for (int k = 0; k < H / 4; ++k) {
            float4 wv = wr[k];
            s0 = fmaf(wv.x, hv[4 * k + 0], s0);
            s1 = fmaf(wv.y, hv[4 * k + 1], s1);
            s2 = fmaf(wv.z, hv[4 * k + 2], s2);
            s3 = fmaf(wv.w, hv[4 * k + 3], s3);
        }
        float acc = bfc[o] + (s0 + s1) + (s2 + s3);
        out[(size_t)(b0 + e) * NOUT + o] = fmaxf(acc, 0.0f);
    }
}

extern "C" void kernel_launch(void* const* d_in, const int* in_sizes, int n_in,
                              void* d_out, int out_size, void* d_ws, size_t ws_size,
                              hipStream_t stream) {
    const float* x    = (const float*)d_in[0];
    const float* Wih0 = (const float*)d_in[1];
    const float* Whh0 = (const float*)d_in[2];
    const float* bih0 = (const float*)d_in[3];
    const float* bhh0 = (const float*)d_in[4];
    const float* Wih1 = (const float*)d_in[5];
    const float* Whh1 = (const float*)d_in[6];
    const float* bih1 = (const float*)d_in[7];
    const float* bhh1 = (const float*)d_in[8];
    const float* Wfc  = (const float*)d_in[9];
    const float* bfc  = (const float*)d_in[10];
    float* out = (float*)d_out;

    lstm_pipe<<<dim3(BATCH / BT), dim3(512), 0, stream>>>(
        x, Wih0, Whh0, bih0, bhh0, Wih1, Whh1, bih1, bhh1, Wfc, bfc, out);
}

// Round 11
// 988.582 us; speedup vs baseline: 1.3062x; 1.1919x over previous
//
#include <hip/hip_runtime.h>
#include <math.h>

#define BATCH 1024
#define TSEQ  2048
#define DIN   5
#define H     64
#define BT    4      // elems per block; grid 256 = every CU
#define SSTR  144    // halves/elem: [h1 64 | h2 64 | pad 16] = 72 words -> exact 2-way banks (free)
#define NOUT  128

typedef _Float16 f16x8 __attribute__((ext_vector_type(8)));
typedef float    f32x4 __attribute__((ext_vector_type(4)));

#if __has_builtin(__builtin_amdgcn_rcpf)
__device__ __forceinline__ float rcp_fast(float x) { return __builtin_amdgcn_rcpf(x); }
#else
__device__ __forceinline__ float rcp_fast(float x) { return 1.0f / x; }
#endif

#define LOG2E 1.44269504088896f

// exp2-based activations; weights/biases pre-scaled by log2e (sigmoid) or
// 2*log2e (tanh gate) so no per-use multiply.
__device__ __forceinline__ float sigm2(float s) {   // s = log2e * p
    return rcp_fast(1.0f + __builtin_amdgcn_exp2f(-s));
}
__device__ __forceinline__ float tanh2(float s) {   // s = 2*log2e * p
    return fmaf(-2.0f, rcp_fast(__builtin_amdgcn_exp2f(s) + 1.0f), 1.0f);
}

// r8 skeleton (512 thr = 8 waves, BT=4, grid 256, layer-split waves, barrier)
// with the critical chain shortened:
//  - x lives in REGISTERS (global->reg prefetch), not LDS; its MFMA
//    contribution dx[g] = mfma(ax, Bx[g], bias) is precomputed one iter early
//    -> lay-1 post-barrier chain is ds_read + 2 MFMAs + gates.
//  - state = [h1|h2] only, stride 144 halves: all b128 reads exact 2-way.
//  - loop-invariant lane addresses hoisted; no ring arithmetic.
// A = state with elem = m>>2 -> D reg 0 is elem q for every lane (no selects).
__global__ __launch_bounds__(512)
void lstm_mfma(const float* __restrict__ x,
               const float* __restrict__ Wih0, const float* __restrict__ Whh0,
               const float* __restrict__ bih0, const float* __restrict__ bhh0,
               const float* __restrict__ Wih1, const float* __restrict__ Whh1,
               const float* __restrict__ bih1, const float* __restrict__ bhh1,
               const float* __restrict__ Wfc,  const float* __restrict__ bfc,
               float* __restrict__ out)
{
    __shared__ alignas(16) _Float16 S[2][BT * SSTR];   // 2.25 KB state, double-buffered
    __shared__ alignas(16) float    h2f[BT][H];        // 1 KB final h2 for FC

    const int tid  = threadIdx.x;
    const int w    = tid >> 6;         // 0..7
    const int lane = tid & 63;
    const int col  = lane & 15;        // n (h-unit offset); A-row m
    const int q    = lane >> 4;        // quad -> G elem; k-slice
    const int ww   = w & 3;            // h-unit tile
    const int lay  = w >> 2;           // 0 = layer-1, 1 = layer-2
    const int hu   = 16 * ww + col;
    const int b0   = blockIdx.x * BT;

    // ---- zero both state buffers ----
    for (int j = tid; j < 2 * BT * SSTR; j += 512)
        ((_Float16*)S)[j] = (_Float16)0.0f;

    const float sgl[4] = {LOG2E, LOG2E, 2.0f * LOG2E, LOG2E};  // i,f,g,o

    // ---- B-fragments for THIS wave's layer (registers, pre-scaled) ----
    // B[k=q*8+j][n=col]; n-tile g = gate rows g*64 + hu.
    // lay0: [0]=Whh0 k0-31 [1]=Whh0 k32-63 [2]=Wih0 (5 of 32; zero for q!=0) [3]=0
    // lay1: [0]=Wih1 k0-31 [1]=Wih1 k32-63 [2]=Whh1 k0-31 [3]=Whh1 k32-63
    f16x8 Bf[4][4];
    f32x4 bC[4];
    #pragma unroll
    for (int g = 0; g < 4; ++g) {
        const int   row = g * 64 + hu;
        const float sg  = sgl[g];
        const float* Wa = lay ? (Wih1 + row * H) : (Whh0 + row * H);
        f16x8 f0, f1, f2, f3;
        #pragma unroll
        for (int j = 0; j < 8; ++j) {
            f0[j] = (_Float16)(Wa[q * 8 + j] * sg);
            f1[j] = (_Float16)(Wa[32 + q * 8 + j] * sg);
        }
        if (lay) {
            const float* Wb = Whh1 + row * H;
            #pragma unroll
            for (int j = 0; j < 8; ++j) {
                f2[j] = (_Float16)(Wb[q * 8 + j] * sg);
                f3[j] = (_Float16)(Wb[32 + q * 8 + j] * sg);
            }
        } else {
            #pragma unroll
            for (int j = 0; j < 8; ++j) {
                const int kk = q * 8 + j;
                f2[j] = (_Float16)(kk < DIN ? Wih0[row * DIN + kk] * sg : 0.0f);
                f3[j] = (_Float16)0.0f;
            }
        }
        Bf[g][0] = f0; Bf[g][1] = f1; Bf[g][2] = f2; Bf[g][3] = f3;
        const float bb = (lay ? (bih1[row] + bhh1[row])
                              : (bih0[row] + bhh0[row])) * sg;
        bC[g] = f32x4{bb, bb, bb, bb};
    }

    // ---- x machinery (lay-0 waves): direct global->reg, dx precomputed ----
    // Only q==0 lanes carry real x (B's k>=8 rows are zero), elem = col>>2.
    const float* xp = x + (size_t)(b0 + (col >> 2)) * TSEQ * DIN;
    f16x8 ax = {(_Float16)0.0f, (_Float16)0.0f, (_Float16)0.0f, (_Float16)0.0f,
                (_Float16)0.0f, (_Float16)0.0f, (_Float16)0.0f, (_Float16)0.0f};
    f32x4 dx[4];
    if (lay == 0) {
        if (q == 0) {   // x(t=0)
            ax[0] = (_Float16)xp[0]; ax[1] = (_Float16)xp[1];
            ax[2] = (_Float16)xp[2]; ax[3] = (_Float16)xp[3];
            ax[4] = (_Float16)xp[4];
        }
        #pragma unroll
        for (int g = 0; g < 4; ++g)
            dx[g] = __builtin_amdgcn_mfma_f32_16x16x32_f16(ax, Bf[g][2], bC[g], 0, 0, 0);
        xp += DIN;      // -> t=1
    }

    const int ab  = (col >> 2) * SSTR + q * 8;   // A-frag read base (halves)
    const int wb1 = q * SSTR + hu;               // h1 write slot
    const int wb2 = q * SSTR + 64 + hu;          // h2 write slot
    float cst = 0.0f, h2fin = 0.0f;

    __syncthreads();

    // ============ main loop: iter i = layer-1(t=i) & layer-2(t=i-1) ============
    #pragma unroll 1
    for (int i = 0; i <= TSEQ; ++i) {
        const _Float16* rb = S[(i + 1) & 1];
        _Float16*       wbuf = S[i & 1];

        if (lay == 0) {
            // fire next-x loads first (latency hidden under MFMA+G)
            const bool xld = (q == 0) && (i + 1 < TSEQ);
            float x0, x1, x2, x3, x4;
            if (xld) { x0 = xp[0]; x1 = xp[1]; x2 = xp[2]; x3 = xp[3]; x4 = xp[4]; }

            f16x8 a0 = *(const f16x8*)&rb[ab];        // h1 k 0..31
            f16x8 a1 = *(const f16x8*)&rb[ab + 32];   // h1 k 32..63
            f32x4 d[4];
            #pragma unroll
            for (int g = 0; g < 4; ++g) {             // 2-deep chain (dx has x+bias)
                d[g] = __builtin_amdgcn_mfma_f32_16x16x32_f16(a0, Bf[g][0], dx[g], 0, 0, 0);
                d[g] = __builtin_amdgcn_mfma_f32_16x16x32_f16(a1, Bf[g][1], d[g], 0, 0, 0);
            }
            if (i < TSEQ) {   // layer-1 G for t=i
                float iv = sigm2(d[0][0]);
                float fv = sigm2(d[1][0]);
                float gv = tanh2(d[2][0]);
                float ov = sigm2(d[3][0]);
                cst = fmaf(fv, cst, iv * gv);
                wbuf[wb1] = (_Float16)(ov * tanh2(2.0f * LOG2E * cst));
            }
            // prep dx for t=i+1 (off the critical path)
            if (xld) {
                ax[0] = (_Float16)x0; ax[1] = (_Float16)x1;
                ax[2] = (_Float16)x2; ax[3] = (_Float16)x3;
                ax[4] = (_Float16)x4;
            }
            #pragma unroll
            for (int g = 0; g < 4; ++g)
                dx[g] = __builtin_amdgcn_mfma_f32_16x16x32_f16(ax, Bf[g][2], bC[g], 0, 0, 0);
            xp += DIN;
        } else {
            f16x8 ay0 = *(const f16x8*)&rb[ab];        // y1(t-1) k 0..31
            f16x8 ay1 = *(const f16x8*)&rb[ab + 32];   // y1(t-1) k 32..63
            f16x8 ah0 = *(const f16x8*)&rb[ab + 64];   // h2(t-2) k 0..31
            f16x8 ah1 = *(const f16x8*)&rb[ab + 96];   // h2(t-2) k 32..63
            f32x4 d[4];
            #pragma unroll
            for (int g = 0; g < 4; ++g) {
                d[g] = __builtin_amdgcn_mfma_f32_16x16x32_f16(ay0, Bf[g][0], bC[g], 0, 0, 0);
                d[g] = __builtin_amdgcn_mfma_f32_16x16x32_f16(ay1, Bf[g][1], d[g], 0, 0, 0);
                d[g] = __builtin_amdgcn_mfma_f32_16x16x32_f16(ah0, Bf[g][2], d[g], 0, 0, 0);
                d[g] = __builtin_amdgcn_mfma_f32_16x16x32_f16(ah1, Bf[g][3], d[g], 0, 0, 0);
            }
            if (i > 0) {      // layer-2 G for t=i-1
                float iv = sigm2(d[0][0]);
                float fv = sigm2(d[1][0]);
                float gv = tanh2(d[2][0]);
                float ov = sigm2(d[3][0]);
                cst = fmaf(fv, cst, iv * gv);
                h2fin = ov * tanh2(2.0f * LOG2E * cst);
                wbuf[wb2] = (_Float16)h2fin;
            }
        }
        __syncthreads();
    }

    // ---------------- epilogue: out = relu(h2(T-1) @ Wfc^T + bfc) ----------------
    if (lay) h2f[q][hu] = h2fin;
    __syncthreads();
    {
        const int e = tid >> 7;            // 0..3
        const int o = tid & (NOUT - 1);    // 0..127
        const float4* wr = (const float4*)(Wfc + o * H);
        const float*  hv = h2f[e];
        float s0 = 0.f, s1 = 0.f, s2 = 0.f, s3 = 0.f;
        #pragma unroll
        for (int k = 0; k < H / 4; ++k) {
            float4 wv = wr[k];
            s0 = fmaf(wv.x, hv[4 * k + 0], s0);
            s1 = fmaf(wv.y, hv[4 * k + 1], s1);
            s2 = fmaf(wv.z, hv[4 * k + 2], s2);
            s3 = fmaf(wv.w, hv[4 * k + 3], s3);
        }
        float acc = bfc[o] + (s0 + s1) + (s2 + s3);
        out[(size_t)(b0 + e) * NOUT + o] = fmaxf(acc, 0.0f);
    }
}

extern "C" void kernel_launch(void* const* d_in, const int* in_sizes, int n_in,
                              void* d_out, int out_size, void* d_ws, size_t ws_size,
                              hipStream_t stream) {
    const float* x    = (const float*)d_in[0];
    const float* Wih0 = (const float*)d_in[1];
    const float* Whh0 = (const float*)d_in[2];
    const float* bih0 = (const float*)d_in[3];
    const float* bhh0 = (const float*)d_in[4];
    const float* Wih1 = (const float*)d_in[5];
    const float* Whh1 = (const float*)d_in[6];
    const float* bih1 = (const float*)d_in[7];
    const float* bhh1 = (const float*)d_in[8];
    const float* Wfc  = (const float*)d_in[9];
    const float* bfc  = (const float*)d_in[10];
    float* out = (float*)d_out;

    lstm_mfma<<<dim3(BATCH / BT), dim3(512), 0, stream>>>(
        x, Wih0, Whh0, bih0, bhh0, Wih1, Whh1, bih1, bhh1, Wfc, bfc, out);
}